// Round 8
// baseline (407.100 us; speedup 1.0000x reference)
//
#include <hip/hip_runtime.h>
#include <hip/hip_cooperative_groups.h>
#include <math.h>

namespace cg = cooperative_groups;

#define NN 8
#define CC 96
#define HH 256
#define WW 256
#define GG 2
#define KK 3
#define CPG (CC / GG)
#define HWD (HH * WW)
#define CHUNKS 8
#define NCHUNK (NN * CC * CHUNKS)     // 6144 phase-1 work items
#define NROWBLK (NN * CC * (HH / 16)) // 12288 phase-3 work items (16 rows each)

typedef float fvec4 __attribute__((ext_vector_type(4)));

// ===========================================================================
// Persistent cooperative kernel. Grid = resident capacity (host occupancy
// query, target 2048 blocks = 8/CU = 32 waves/CU). ALL phases grid-stride,
// so ANY resident block count is correct.
//   Phase 1: 6144 chunk partial-sums of x -> mp   (regular loads: fill L3)
//   sync
//   Phase 2: 48 blocks each compute one filt tap -> filt
//   sync
//   Phase 3: 12288 row-blocks (16 rows): conv + gap + epilogue.
//            Regular loads (hit the L3 copy phase 1 left; R6 proved NT loads
//            bypass it), NT stores (R3 proved they help; out must not evict x).
// ===========================================================================
__global__ __launch_bounds__(256, 8) void fused_kernel(
    const float* __restrict__ x, const float* __restrict__ Wconv,
    const float* __restrict__ inside_all, const float* __restrict__ lamb_l,
    const float* __restrict__ lamb_h, float* __restrict__ out,
    float* __restrict__ mp, float* __restrict__ filt, int nblocks) {
    const int t = threadIdx.x;
    const int wave = t >> 6;
    const int lane = t & 63;
    __shared__ float ls[4];
    __shared__ float acc_sh[CC];
    cg::grid_group grid = cg::this_grid();

    // ---- Phase 1: chunk partial sums (MLP=4 via unroll) ----
    for (int b = blockIdx.x; b < NCHUNK; b += nblocks) {
        const int nc = b >> 3;
        const int chunk = b & 7;
        const fvec4* xp = (const fvec4*)x + (size_t)nc * (HWD / 4)
                          + (size_t)chunk * (HWD / 4 / CHUNKS);
        float s = 0.f;
#pragma unroll 4
        for (int i = 0; i < HWD / 4 / CHUNKS / 256; ++i) {  // 8 iters
            fvec4 v = xp[i * 256 + t];
            s += (v.x + v.y) + (v.z + v.w);
        }
#pragma unroll
        for (int off = 32; off; off >>= 1) s += __shfl_down(s, off, 64);
        if (lane == 0) ls[wave] = s;
        __syncthreads();
        if (t == 0) mp[b] = (ls[0] + ls[1]) + (ls[2] + ls[3]);
        __syncthreads();  // protect ls before next grid-stride iteration
    }
    __threadfence();
    grid.sync();

    // ---- Phase 2: 48 blocks, one filter tap each ----
    if (blockIdx.x < NN * GG * KK) {
        const int n = blockIdx.x / (GG * KK);
        const int gk = blockIdx.x % (GG * KK);
        if (t < CC) {
            const float* pr = mp + ((size_t)n * CC + t) * CHUNKS;
            float a0 = 0.f;
#pragma unroll
            for (int k = 0; k < CHUNKS; ++k) a0 += pr[k];
            acc_sh[t] = a0 * Wconv[gk * CC + t];
        }
        __syncthreads();
        if (t == 0) {
            float acc = 0.f;
            for (int j = 0; j < CC; ++j) acc += acc_sh[j];
            filt[blockIdx.x] = tanhf(acc * (1.0f / (float)HWD));
        }
    }
    __threadfence();
    grid.sync();

    // ---- Phase 3: row-blocks of 16 rows, MLP=4 per wave ----
    for (int bb = blockIdx.x; bb < NROWBLK; bb += nblocks) {
        const int nc = bb >> 4;
        const int rblk = bb & 15;
        const int c = nc % CC;
        const int n = nc / CC;
        const int g = c / CPG;

        const float* fr = filt + (n * GG + g) * KK;
        const float f0 = fr[0], f1 = fr[1], f2 = fr[2];
        const float ia = inside_all[c];
        const float ll = lamb_l[c];
        const float lh1 = lamb_h[c] + 1.0f;
        const float a = ia + 1.0f;

        const int row0 = (rblk << 4) + (wave << 2);
        const size_t base = ((size_t)nc * HH + row0) * WW;
        fvec4 v0 = ((const fvec4*)(x + base + 0 * WW))[lane];
        fvec4 v1 = ((const fvec4*)(x + base + 1 * WW))[lane];
        fvec4 v2 = ((const fvec4*)(x + base + 2 * WW))[lane];
        fvec4 v3 = ((const fvec4*)(x + base + 3 * WW))[lane];

        float s0 = (v0.x + v0.y) + (v0.z + v0.w);
        float s1 = (v1.x + v1.y) + (v1.z + v1.w);
        float s2 = (v2.x + v2.y) + (v2.z + v2.w);
        float s3 = (v3.x + v3.y) + (v3.z + v3.w);
#pragma unroll
        for (int off = 1; off < 64; off <<= 1) {
            s0 += __shfl_xor(s0, off, 64);
            s1 += __shfl_xor(s1, off, 64);
            s2 += __shfl_xor(s2, off, 64);
            s3 += __shfl_xor(s3, off, 64);
        }

#pragma unroll
        for (int r = 0; r < 4; ++r) {
            const fvec4 v = (r == 0) ? v0 : (r == 1) ? v1 : (r == 2) ? v2 : v3;
            const float rs = (r == 0) ? s0 : (r == 1) ? s1 : (r == 2) ? s2 : s3;
            const float gap = rs * (1.0f / (float)WW);

            const float left = __shfl_up(v.w, 1, 64);
            const float right = __shfl_down(v.x, 1, 64);
            const float xm1 = (lane == 0) ? v.y : left;    // x[-1]=x[1]
            const float xp1 = (lane == 63) ? v.z : right;  // x[W]=x[W-2]

            const float c0 = f0 * xm1 + f1 * v.x + f2 * v.y;
            const float c1 = f0 * v.x + f1 * v.y + f2 * v.z;
            const float c2 = f0 * v.y + f1 * v.z + f2 * v.w;
            const float c3 = f0 * v.z + f1 * v.w + f2 * xp1;

            const float bterm = ia * gap;
            fvec4 o;
            o.x = (c0 * a - bterm) * ll + v.x * lh1;
            o.y = (c1 * a - bterm) * ll + v.y * lh1;
            o.z = (c2 * a - bterm) * ll + v.z * lh1;
            o.w = (c3 * a - bterm) * ll + v.w * lh1;
            __builtin_nontemporal_store(o, (fvec4*)(out + base + r * WW) + lane);
        }
    }
}

// ===========================================================================
// Fallback: proven ~93 us two-kernel path.
// ===========================================================================
__global__ __launch_bounds__(256) void partial_kernel(
    const float* __restrict__ x, float* __restrict__ mp) {
    const int b = blockIdx.x;
    const int nc = b >> 3;
    const int chunk = b & 7;
    const int t = threadIdx.x;
    const fvec4* xp = (const fvec4*)x + (size_t)nc * (HWD / 4)
                      + (size_t)chunk * (HWD / 4 / CHUNKS);
    float s = 0.f;
#pragma unroll
    for (int i = 0; i < HWD / 4 / CHUNKS / 256; ++i) {
        fvec4 v = xp[i * 256 + t];
        s += (v.x + v.y) + (v.z + v.w);
    }
#pragma unroll
    for (int off = 32; off; off >>= 1) s += __shfl_down(s, off, 64);
    __shared__ float ls[4];
    if ((t & 63) == 0) ls[t >> 6] = s;
    __syncthreads();
    if (t == 0) mp[b] = (ls[0] + ls[1]) + (ls[2] + ls[3]);
}

__global__ __launch_bounds__(256) void main_kernel(
    const float* __restrict__ x, const float* __restrict__ mp,
    const float* __restrict__ Wconv, const float* __restrict__ inside_all,
    const float* __restrict__ lamb_l, const float* __restrict__ lamb_h,
    float* __restrict__ out) {
    const int bb = blockIdx.x;
    const int nc = bb >> 4;
    const int rblk = bb & 15;
    const int t = threadIdx.x;
    const int wave = t >> 6;
    const int lane = t & 63;
    const int c = nc % CC;
    const int n = nc / CC;
    const int g = c / CPG;

    __shared__ float msh[CC];
    __shared__ float fsh[KK];
    if (t < CC) {
        const float* pr = mp + ((size_t)n * CC + t) * CHUNKS;
        float a0 = 0.f;
#pragma unroll
        for (int k = 0; k < CHUNKS; ++k) a0 += pr[k];
        msh[t] = a0;
    }
    __syncthreads();
    if (t < KK) {
        const float* Wr = Wconv + (g * KK + t) * CC;
        float acc = 0.f;
#pragma unroll
        for (int j = 0; j < CC; ++j) acc += msh[j] * Wr[j];
        fsh[t] = tanhf(acc * (1.0f / (float)HWD));
    }
    __syncthreads();
    const float f0 = fsh[0], f1 = fsh[1], f2 = fsh[2];
    const float ia = inside_all[c];
    const float ll = lamb_l[c];
    const float lh1 = lamb_h[c] + 1.0f;
    const float a = ia + 1.0f;

    const int row0 = (rblk << 4) + (wave << 2);
    const size_t base = ((size_t)nc * HH + row0) * WW;
    fvec4 v0 = ((const fvec4*)(x + base + 0 * WW))[lane];
    fvec4 v1 = ((const fvec4*)(x + base + 1 * WW))[lane];
    fvec4 v2 = ((const fvec4*)(x + base + 2 * WW))[lane];
    fvec4 v3 = ((const fvec4*)(x + base + 3 * WW))[lane];

    float s0 = (v0.x + v0.y) + (v0.z + v0.w);
    float s1 = (v1.x + v1.y) + (v1.z + v1.w);
    float s2 = (v2.x + v2.y) + (v2.z + v2.w);
    float s3 = (v3.x + v3.y) + (v3.z + v3.w);
#pragma unroll
    for (int off = 1; off < 64; off <<= 1) {
        s0 += __shfl_xor(s0, off, 64);
        s1 += __shfl_xor(s1, off, 64);
        s2 += __shfl_xor(s2, off, 64);
        s3 += __shfl_xor(s3, off, 64);
    }
#pragma unroll
    for (int r = 0; r < 4; ++r) {
        const fvec4 v = (r == 0) ? v0 : (r == 1) ? v1 : (r == 2) ? v2 : v3;
        const float rs = (r == 0) ? s0 : (r == 1) ? s1 : (r == 2) ? s2 : s3;
        const float gap = rs * (1.0f / (float)WW);
        const float left = __shfl_up(v.w, 1, 64);
        const float right = __shfl_down(v.x, 1, 64);
        const float xm1 = (lane == 0) ? v.y : left;
        const float xp1 = (lane == 63) ? v.z : right;
        const float c0 = f0 * xm1 + f1 * v.x + f2 * v.y;
        const float c1 = f0 * v.x + f1 * v.y + f2 * v.z;
        const float c2 = f0 * v.y + f1 * v.z + f2 * v.w;
        const float c3 = f0 * v.z + f1 * v.w + f2 * xp1;
        const float bterm = ia * gap;
        fvec4 o;
        o.x = (c0 * a - bterm) * ll + v.x * lh1;
        o.y = (c1 * a - bterm) * ll + v.y * lh1;
        o.z = (c2 * a - bterm) * ll + v.z * lh1;
        o.w = (c3 * a - bterm) * ll + v.w * lh1;
        __builtin_nontemporal_store(o, (fvec4*)(out + base + r * WW) + lane);
    }
}

// ===========================================================================
extern "C" void kernel_launch(void* const* d_in, const int* in_sizes, int n_in,
                              void* d_out, int out_size, void* d_ws,
                              size_t ws_size, hipStream_t stream) {
    const float* x = (const float*)d_in[0];
    const float* Wconv = (const float*)d_in[1];
    const float* inside_all = (const float*)d_in[2];
    const float* lamb_l = (const float*)d_in[3];
    const float* lamb_h = (const float*)d_in[4];
    float* out = (float*)d_out;
    float* mp = (float*)d_ws;            // NCHUNK floats
    float* filt = mp + NCHUNK;           // NN*GG*KK floats

    // Host-side capacity sizing (capture-safe queries, deterministic).
    int maxblk = 0, ncu = 0;
    hipError_t q1 = hipOccupancyMaxActiveBlocksPerMultiprocessor(
        &maxblk, fused_kernel, 256, 0);
    hipError_t q2 = hipDeviceGetAttribute(
        &ncu, hipDeviceAttributeMultiprocessorCount, 0);
    int nblocks = maxblk * ncu;
    if (nblocks > 2048) nblocks = 2048;

    if (q1 == hipSuccess && q2 == hipSuccess && nblocks >= 64) {
        void* kargs[] = {(void*)&x,      (void*)&Wconv, (void*)&inside_all,
                         (void*)&lamb_l, (void*)&lamb_h, (void*)&out,
                         (void*)&mp,     (void*)&filt,  (void*)&nblocks};
        hipLaunchCooperativeKernel(fused_kernel, dim3(nblocks), dim3(256),
                                   kargs, 0, stream);
    } else {
        partial_kernel<<<NCHUNK, 256, 0, stream>>>(x, mp);
        main_kernel<<<NROWBLK, 256, 0, stream>>>(x, mp, Wconv, inside_all,
                                                 lamb_l, lamb_h, out);
    }
}

// Round 9
// 95.790 us; speedup vs baseline: 4.2499x; 4.2499x over previous
//
#include <hip/hip_runtime.h>
#include <math.h>

#define NN 8
#define CC 96
#define HH 256
#define WW 256
#define GG 2
#define KK 3
#define CPG (CC / GG)
#define HWD (HH * WW)
#define CHUNKS 8
#define NCHUNK (NN * CC * CHUNKS)     // 6144 phase-1 work items
#define NROWBLK (NN * CC * (HH / 16)) // 12288 main-pass work items

typedef float fvec4 __attribute__((ext_vector_type(4)));
typedef unsigned int uvec2 __attribute__((ext_vector_type(2)));

__device__ __forceinline__ unsigned pack_bf16(float a, float b) {
    unsigned ua = __float_as_uint(a);
    unsigned ub = __float_as_uint(b);
    ua = (ua + 0x7FFFu + ((ua >> 16) & 1u)) >> 16;          // RNE to bf16
    ub = (ub + 0x7FFFu + ((ub >> 16) & 1u)) & 0xFFFF0000u;  // keep in high half
    return (ua & 0xFFFFu) | ub;
}

// ---------------------------------------------------------------------------
// Kernel A: partial sums + bf16 pack. 6144 blocks (8 chunks per (n,c) slice).
// x is read with NON-TEMPORAL loads (no L3 allocation — R6 showed NT loads
// bypass L3; here that's desired: keep L3 free for the bf16 copy).
// The bf16 copy is written with REGULAR stores -> resident in L2/L3 (96 MB
// fits in the 256 MiB L3 with room to spare) for kernel B to consume.
// Partial sums computed from the ORIGINAL fp32 values (matches reference).
// ---------------------------------------------------------------------------
__global__ __launch_bounds__(256) void pack_partial_kernel(
    const float* __restrict__ x, unsigned* __restrict__ x16,
    float* __restrict__ mp) {
    const int b = blockIdx.x;           // 0 .. NCHUNK-1
    const int nc = b >> 3;
    const int chunk = b & 7;
    const int t = threadIdx.x;
    const size_t base4 = (size_t)nc * (HWD / 4) + (size_t)chunk * (HWD / 4 / CHUNKS);
    const fvec4* xp = (const fvec4*)x + base4;
    uvec2* wp = (uvec2*)x16 + base4;    // one uvec2 (4 bf16) per fvec4
    float s = 0.f;
#pragma unroll
    for (int i = 0; i < HWD / 4 / CHUNKS / 256; ++i) {  // 8 iters
        fvec4 v = __builtin_nontemporal_load(xp + i * 256 + t);
        s += (v.x + v.y) + (v.z + v.w);
        uvec2 p;
        p.x = pack_bf16(v.x, v.y);
        p.y = pack_bf16(v.z, v.w);
        wp[i * 256 + t] = p;            // regular store: allocate in L2/L3
    }
#pragma unroll
    for (int off = 32; off; off >>= 1) s += __shfl_down(s, off, 64);
    __shared__ float ls[4];
    if ((t & 63) == 0) ls[t >> 6] = s;
    __syncthreads();
    if (t == 0) mp[b] = (ls[0] + ls[1]) + (ls[2] + ls[3]);
}

// ---------------------------------------------------------------------------
// Kernel B: main pass reading the L3-resident bf16 copy (8 B/lane loads),
// NT stores for out (don't pollute L3). Prologue rebuilds the 3 taps.
// ---------------------------------------------------------------------------
__global__ __launch_bounds__(256) void main16_kernel(
    const unsigned* __restrict__ x16, const float* __restrict__ mp,
    const float* __restrict__ Wconv, const float* __restrict__ inside_all,
    const float* __restrict__ lamb_l, const float* __restrict__ lamb_h,
    float* __restrict__ out) {
    const int bb = blockIdx.x;
    const int nc = bb >> 4;             // 16 blocks per (n,c)
    const int rblk = bb & 15;
    const int t = threadIdx.x;
    const int wave = t >> 6;
    const int lane = t & 63;
    const int c = nc % CC;
    const int n = nc / CC;
    const int g = c / CPG;

    __shared__ float msh[CC];
    __shared__ float fsh[KK];
    if (t < CC) {
        const float* pr = mp + ((size_t)n * CC + t) * CHUNKS;
        float a0 = 0.f;
#pragma unroll
        for (int k = 0; k < CHUNKS; ++k) a0 += pr[k];
        msh[t] = a0;
    }
    __syncthreads();
    if (t < KK) {
        const float* Wr = Wconv + (g * KK + t) * CC;
        float acc = 0.f;
#pragma unroll
        for (int j = 0; j < CC; ++j) acc += msh[j] * Wr[j];
        fsh[t] = tanhf(acc * (1.0f / (float)HWD));
    }
    __syncthreads();
    const float f0 = fsh[0], f1 = fsh[1], f2 = fsh[2];
    const float ia = inside_all[c];
    const float ll = lamb_l[c];
    const float lh1 = lamb_h[c] + 1.0f;
    const float a = ia + 1.0f;

    const int row0 = (rblk << 4) + (wave << 2);
    const size_t base = ((size_t)nc * HH + row0) * WW;
    const uvec2* xq = (const uvec2*)x16 + (base >> 2);
    // 4 rows per wave, 4 independent 8B loads in flight
    uvec2 q0 = xq[(0 * WW >> 2) + lane];
    uvec2 q1 = xq[(1 * WW >> 2) + lane];
    uvec2 q2 = xq[(2 * WW >> 2) + lane];
    uvec2 q3 = xq[(3 * WW >> 2) + lane];

#define UNPK(q, v)                                    \
    v.x = __uint_as_float(q.x << 16);                 \
    v.y = __uint_as_float(q.x & 0xFFFF0000u);         \
    v.z = __uint_as_float(q.y << 16);                 \
    v.w = __uint_as_float(q.y & 0xFFFF0000u);
    fvec4 v0, v1, v2, v3;
    UNPK(q0, v0) UNPK(q1, v1) UNPK(q2, v2) UNPK(q3, v3)
#undef UNPK

    float s0 = (v0.x + v0.y) + (v0.z + v0.w);
    float s1 = (v1.x + v1.y) + (v1.z + v1.w);
    float s2 = (v2.x + v2.y) + (v2.z + v2.w);
    float s3 = (v3.x + v3.y) + (v3.z + v3.w);
#pragma unroll
    for (int off = 1; off < 64; off <<= 1) {
        s0 += __shfl_xor(s0, off, 64);
        s1 += __shfl_xor(s1, off, 64);
        s2 += __shfl_xor(s2, off, 64);
        s3 += __shfl_xor(s3, off, 64);
    }

#pragma unroll
    for (int r = 0; r < 4; ++r) {
        const fvec4 v = (r == 0) ? v0 : (r == 1) ? v1 : (r == 2) ? v2 : v3;
        const float rs = (r == 0) ? s0 : (r == 1) ? s1 : (r == 2) ? s2 : s3;
        const float gap = rs * (1.0f / (float)WW);

        const float left = __shfl_up(v.w, 1, 64);
        const float right = __shfl_down(v.x, 1, 64);
        const float xm1 = (lane == 0) ? v.y : left;    // reflect: x[-1]=x[1]
        const float xp1 = (lane == 63) ? v.z : right;  // reflect: x[W]=x[W-2]

        const float c0 = f0 * xm1 + f1 * v.x + f2 * v.y;
        const float c1 = f0 * v.x + f1 * v.y + f2 * v.z;
        const float c2 = f0 * v.y + f1 * v.z + f2 * v.w;
        const float c3 = f0 * v.z + f1 * v.w + f2 * xp1;

        const float bterm = ia * gap;
        fvec4 o;
        o.x = (c0 * a - bterm) * ll + v.x * lh1;
        o.y = (c1 * a - bterm) * ll + v.y * lh1;
        o.z = (c2 * a - bterm) * ll + v.z * lh1;
        o.w = (c3 * a - bterm) * ll + v.w * lh1;
        __builtin_nontemporal_store(o, (fvec4*)(out + base + r * WW) + lane);
    }
}

// ===========================================================================
// Fallback (proven ~93 us): fp32 two-kernel path, used only if ws too small.
// ===========================================================================
__global__ __launch_bounds__(256) void partial_kernel(
    const float* __restrict__ x, float* __restrict__ mp) {
    const int b = blockIdx.x;
    const int nc = b >> 3;
    const int chunk = b & 7;
    const int t = threadIdx.x;
    const fvec4* xp = (const fvec4*)x + (size_t)nc * (HWD / 4)
                      + (size_t)chunk * (HWD / 4 / CHUNKS);
    float s = 0.f;
#pragma unroll
    for (int i = 0; i < HWD / 4 / CHUNKS / 256; ++i) {
        fvec4 v = xp[i * 256 + t];
        s += (v.x + v.y) + (v.z + v.w);
    }
#pragma unroll
    for (int off = 32; off; off >>= 1) s += __shfl_down(s, off, 64);
    __shared__ float ls[4];
    if ((t & 63) == 0) ls[t >> 6] = s;
    __syncthreads();
    if (t == 0) mp[b] = (ls[0] + ls[1]) + (ls[2] + ls[3]);
}

__global__ __launch_bounds__(256) void main_kernel(
    const float* __restrict__ x, const float* __restrict__ mp,
    const float* __restrict__ Wconv, const float* __restrict__ inside_all,
    const float* __restrict__ lamb_l, const float* __restrict__ lamb_h,
    float* __restrict__ out) {
    const int bb = blockIdx.x;
    const int nc = bb >> 4;
    const int rblk = bb & 15;
    const int t = threadIdx.x;
    const int wave = t >> 6;
    const int lane = t & 63;
    const int c = nc % CC;
    const int n = nc / CC;
    const int g = c / CPG;

    __shared__ float msh[CC];
    __shared__ float fsh[KK];
    if (t < CC) {
        const float* pr = mp + ((size_t)n * CC + t) * CHUNKS;
        float a0 = 0.f;
#pragma unroll
        for (int k = 0; k < CHUNKS; ++k) a0 += pr[k];
        msh[t] = a0;
    }
    __syncthreads();
    if (t < KK) {
        const float* Wr = Wconv + (g * KK + t) * CC;
        float acc = 0.f;
#pragma unroll
        for (int j = 0; j < CC; ++j) acc += msh[j] * Wr[j];
        fsh[t] = tanhf(acc * (1.0f / (float)HWD));
    }
    __syncthreads();
    const float f0 = fsh[0], f1 = fsh[1], f2 = fsh[2];
    const float ia = inside_all[c];
    const float ll = lamb_l[c];
    const float lh1 = lamb_h[c] + 1.0f;
    const float a = ia + 1.0f;

    const int row0 = (rblk << 4) + (wave << 2);
    const size_t base = ((size_t)nc * HH + row0) * WW;
    fvec4 v0 = ((const fvec4*)(x + base + 0 * WW))[lane];
    fvec4 v1 = ((const fvec4*)(x + base + 1 * WW))[lane];
    fvec4 v2 = ((const fvec4*)(x + base + 2 * WW))[lane];
    fvec4 v3 = ((const fvec4*)(x + base + 3 * WW))[lane];

    float s0 = (v0.x + v0.y) + (v0.z + v0.w);
    float s1 = (v1.x + v1.y) + (v1.z + v1.w);
    float s2 = (v2.x + v2.y) + (v2.z + v2.w);
    float s3 = (v3.x + v3.y) + (v3.z + v3.w);
#pragma unroll
    for (int off = 1; off < 64; off <<= 1) {
        s0 += __shfl_xor(s0, off, 64);
        s1 += __shfl_xor(s1, off, 64);
        s2 += __shfl_xor(s2, off, 64);
        s3 += __shfl_xor(s3, off, 64);
    }
#pragma unroll
    for (int r = 0; r < 4; ++r) {
        const fvec4 v = (r == 0) ? v0 : (r == 1) ? v1 : (r == 2) ? v2 : v3;
        const float rs = (r == 0) ? s0 : (r == 1) ? s1 : (r == 2) ? s2 : s3;
        const float gap = rs * (1.0f / (float)WW);
        const float left = __shfl_up(v.w, 1, 64);
        const float right = __shfl_down(v.x, 1, 64);
        const float xm1 = (lane == 0) ? v.y : left;
        const float xp1 = (lane == 63) ? v.z : right;
        const float c0 = f0 * xm1 + f1 * v.x + f2 * v.y;
        const float c1 = f0 * v.x + f1 * v.y + f2 * v.z;
        const float c2 = f0 * v.y + f1 * v.z + f2 * v.w;
        const float c3 = f0 * v.z + f1 * v.w + f2 * xp1;
        const float bterm = ia * gap;
        fvec4 o;
        o.x = (c0 * a - bterm) * ll + v.x * lh1;
        o.y = (c1 * a - bterm) * ll + v.y * lh1;
        o.z = (c2 * a - bterm) * ll + v.z * lh1;
        o.w = (c3 * a - bterm) * ll + v.w * lh1;
        __builtin_nontemporal_store(o, (fvec4*)(out + base + r * WW) + lane);
    }
}

// ===========================================================================
extern "C" void kernel_launch(void* const* d_in, const int* in_sizes, int n_in,
                              void* d_out, int out_size, void* d_ws,
                              size_t ws_size, hipStream_t stream) {
    const float* x = (const float*)d_in[0];
    const float* Wconv = (const float*)d_in[1];
    const float* inside_all = (const float*)d_in[2];
    const float* lamb_l = (const float*)d_in[3];
    const float* lamb_h = (const float*)d_in[4];
    float* out = (float*)d_out;

    const size_t x16_bytes = (size_t)NN * CC * HWD * 2;  // 96 MiB bf16 copy
    const size_t need = x16_bytes + (size_t)NCHUNK * 4 + 64;

    if (ws_size >= need) {
        unsigned* x16 = (unsigned*)d_ws;
        float* mp = (float*)((char*)d_ws + x16_bytes);
        pack_partial_kernel<<<NCHUNK, 256, 0, stream>>>(x, x16, mp);
        main16_kernel<<<NROWBLK, 256, 0, stream>>>(x16, mp, Wconv, inside_all,
                                                   lamb_l, lamb_h, out);
    } else {
        float* mp = (float*)d_ws;
        partial_kernel<<<NCHUNK, 256, 0, stream>>>(x, mp);
        main_kernel<<<NROWBLK, 256, 0, stream>>>(x, mp, Wconv, inside_all,
                                                 lamb_l, lamb_h, out);
    }
}